// Round 1
// baseline (393.521 us; speedup 1.0000x reference)
//
#include <hip/hip_runtime.h>
#include <math.h>

#define BB 32
#define NN 500
#define GG 500
#define HH 128
#define NHEADS 8
#define DD 16
#define KNB 16
#define GT 8           // g-rows per workgroup in pointer kernel
#define NTILES 63      // ceil(500/8)

// ---------------------------------------------------------------------------
// Kernel 1: graph mean + q_graph projection, plus Wsum = Wq_first + Wq_last
// grid = BB+1 blocks x 256
// ---------------------------------------------------------------------------
__global__ __launch_bounds__(256) void prep_kernel(
    const float* __restrict__ emb, const float* __restrict__ Wqg,
    const float* __restrict__ Wqf, const float* __restrict__ Wql,
    float* __restrict__ Wsum, float* __restrict__ qgraph) {
  int b = blockIdx.x;
  int tid = threadIdx.x;
  if (b == BB) {  // last block: Wsum = Wqf + Wql
    for (int i = tid; i < HH * HH; i += 256) Wsum[i] = Wqf[i] + Wql[i];
    return;
  }
  __shared__ float red[256];
  __shared__ float meanv[HH];
  int h = tid & (HH - 1);
  int part = tid >> 7;  // 0 or 1
  float acc = 0.f;
  const float* eb = emb + (size_t)b * NN * HH;
  for (int n = part; n < NN; n += 2) acc += eb[(size_t)n * HH + h];
  red[tid] = acc;
  __syncthreads();
  if (tid < HH) meanv[tid] = (red[tid] + red[tid + HH]) * (1.0f / NN);
  __syncthreads();
  if (tid < HH) {
    const float* wrow = Wqg + tid * HH;
    float s = 0.f;
#pragma unroll 8
    for (int k = 0; k < HH; ++k) s += meanv[k] * wrow[k];
    qgraph[b * HH + tid] = s;
  }
}

// ---------------------------------------------------------------------------
// Kernel 2: generic projection out[row][o] = sum_k A[arow][k]*W[o][k] + bias
//   gather != nullptr : arow = b*NN + gather[row]   (last-node gather)
//   mode 0: no bias;  mode 1: + bias[b*HH + o] (q_graph);  mode 2: + bias[o]
// 500 workgroups x 32 rows; thread computes 4 rows x 4 cols; K staged in
// 32-wide k-slices, k-major LDS so compute reads are float4 / broadcast.
// ---------------------------------------------------------------------------
__global__ __launch_bounds__(256) void proj_kernel(
    const float* __restrict__ A, const int* __restrict__ gather,
    const float* __restrict__ W, const float* __restrict__ bias,
    float* __restrict__ out, int mode) {
  __shared__ float As[32][36];    // [k][row], padded stride (16B aligned)
  __shared__ float Ws[32][132];   // [k][col], padded stride (16B aligned)
  int tid = threadIdx.x;
  int row0 = blockIdx.x * 32;

  float acc[4][4];
#pragma unroll
  for (int i = 0; i < 4; ++i)
#pragma unroll
    for (int j = 0; j < 4; ++j) acc[i][j] = 0.f;

  int cg = tid & 31; int c0 = cg * 4;   // 4 output cols
  int rg = tid >> 5; int r0 = rg * 4;   // 4 rows

  // staging assignment for A: 32 rows x 32 k per slice, one float4 per thread
  int sr = tid >> 3;        // row in tile 0..31
  int skq = tid & 7;        // k-quad 0..7
  int grow = row0 + sr;     // global row (b*GG+g)
  int arow;
  if (gather) {
    int bofr = grow / GG;
    arow = bofr * NN + gather[grow];
  } else {
    arow = grow;
  }
  const float4* Arow4 = (const float4*)(A + (size_t)arow * HH);

  for (int ks = 0; ks < 4; ++ks) {
    int k0 = ks * 32;
    // stage A slice (coalesced global read, transposed LDS write)
    float4 a4 = Arow4[(k0 >> 2) + skq];
    As[skq * 4 + 0][sr] = a4.x;
    As[skq * 4 + 1][sr] = a4.y;
    As[skq * 4 + 2][sr] = a4.z;
    As[skq * 4 + 3][sr] = a4.w;
    // stage W slice: 128 cols x 32 k = 1024 float4 / 256 threads
#pragma unroll
    for (int j = 0; j < 4; ++j) {
      int f = tid + j * 256;
      int o = f >> 3; int kq = f & 7;
      float4 w4 = *(const float4*)(W + (size_t)o * HH + k0 + kq * 4);
      Ws[kq * 4 + 0][o] = w4.x;
      Ws[kq * 4 + 1][o] = w4.y;
      Ws[kq * 4 + 2][o] = w4.z;
      Ws[kq * 4 + 3][o] = w4.w;
    }
    __syncthreads();
#pragma unroll
    for (int k = 0; k < 32; ++k) {
      float4 av = *(const float4*)&As[k][r0];   // broadcast within col-group
      float4 wv = *(const float4*)&Ws[k][c0];   // contiguous
      acc[0][0] += av.x * wv.x; acc[0][1] += av.x * wv.y;
      acc[0][2] += av.x * wv.z; acc[0][3] += av.x * wv.w;
      acc[1][0] += av.y * wv.x; acc[1][1] += av.y * wv.y;
      acc[1][2] += av.y * wv.z; acc[1][3] += av.y * wv.w;
      acc[2][0] += av.z * wv.x; acc[2][1] += av.z * wv.y;
      acc[2][2] += av.z * wv.z; acc[2][3] += av.z * wv.w;
      acc[3][0] += av.w * wv.x; acc[3][1] += av.w * wv.y;
      acc[3][2] += av.w * wv.z; acc[3][3] += av.w * wv.w;
    }
    __syncthreads();
  }

#pragma unroll
  for (int i = 0; i < 4; ++i) {
    int orow = row0 + r0 + i;
    float b0 = 0.f, b1 = 0.f, b2 = 0.f, b3 = 0.f;
    if (mode == 1) {
      int bofr = orow / GG;
      const float* qg = bias + bofr * HH + c0;
      b0 = qg[0]; b1 = qg[1]; b2 = qg[2]; b3 = qg[3];
    } else if (mode == 2) {
      b0 = bias[c0 + 0]; b1 = bias[c0 + 1]; b2 = bias[c0 + 2]; b3 = bias[c0 + 3];
    }
    float4 o4;
    o4.x = acc[i][0] + b0; o4.y = acc[i][1] + b1;
    o4.z = acc[i][2] + b2; o4.w = acc[i][3] + b3;
    *(float4*)(out + (size_t)orow * HH + c0) = o4;
  }
}

// ---------------------------------------------------------------------------
// Kernel 3: per-(b,g) distances + stable top-16 smallest (one wave per row)
// ---------------------------------------------------------------------------
__global__ __launch_bounds__(256) void topk_kernel(
    const float* __restrict__ coords, const int* __restrict__ last_node,
    const float* __restrict__ mask, int* __restrict__ nbr) {
  int lane = threadIdx.x & 63;
  int wid = threadIdx.x >> 6;
  int row = blockIdx.x * 4 + wid;  // b*GG + g
  if (row >= BB * GG) return;
  int b = row / GG;
  int last = last_node[row];
  const float* cb = coords + (size_t)b * NN * 2;
  float lx = cb[(size_t)last * 2 + 0];
  float ly = cb[(size_t)last * 2 + 1];
  const float* mrow = mask + (size_t)row * NN;

  float dv[8];
#pragma unroll
  for (int j = 0; j < 8; ++j) {
    int n = lane + j * 64;
    float d = INFINITY;
    if (n < NN) {
      float dx = lx - cb[n * 2];
      float dy = ly - cb[n * 2 + 1];
      d = sqrtf(dx * dx + dy * dy);       // mirror ref: compare sqrt values
      if (mrow[n] == -INFINITY) d = INFINITY;
    }
    dv[j] = d;
  }

  int mine = 0;
  for (int r = 0; r < KNB; ++r) {
    // local min (lowest n wins ties since j ascending, strict <)
    float bv = dv[0]; int bj = 0;
#pragma unroll
    for (int j = 1; j < 8; ++j) {
      if (dv[j] < bv) { bv = dv[j]; bj = j; }
    }
    int bn = lane + bj * 64;
    // wave argmin with stable (lower index) tie-break
#pragma unroll
    for (int off = 32; off; off >>= 1) {
      float ov = __shfl_xor(bv, off, 64);
      int on = __shfl_xor(bn, off, 64);
      if (ov < bv || (ov == bv && on < bn)) { bv = ov; bn = on; }
    }
    // remove winner from its owner lane's local set (static indices only)
    if ((bn & 63) == lane) {
      int jw = bn >> 6;
#pragma unroll
      for (int j = 0; j < 8; ++j)
        if (j == jw) dv[j] = INFINITY;
    }
    if (lane == r) mine = bn;
  }
  if (lane < KNB) nbr[(size_t)row * KNB + lane] = mine;
}

// ---------------------------------------------------------------------------
// Kernel 4: sparse glimpse attention over 16 neighbors + head concat
// one block of 128 threads per (b,g); thread t: h = t>>4, i/j = t&15
// ---------------------------------------------------------------------------
__global__ __launch_bounds__(128) void attn_kernel(
    const float* __restrict__ Q, const float* __restrict__ Kb,
    const float* __restrict__ Vb, const int* __restrict__ nbr,
    float* __restrict__ AO) {
  int row = blockIdx.x;  // b*GG + g
  int b = row / GG;
  int t = threadIdx.x;
  __shared__ float qs[HH];
  __shared__ int nb[KNB];
  __shared__ float att[HH];
  qs[t] = Q[(size_t)row * HH + t];
  if (t < KNB) nb[t] = nbr[(size_t)row * KNB + t];
  __syncthreads();
  int h = t >> 4;
  int i = t & 15;
  // score(h, neighbor i)
  const float* krow = Kb + ((size_t)b * NN + nb[i]) * HH + h * DD;
  float s = 0.f;
#pragma unroll
  for (int j = 0; j < DD; ++j) s += qs[h * DD + j] * krow[j];
  s *= 0.25f;  // 1/sqrt(16)
  // softmax over the 16-lane group (groups are 16-aligned within the wave)
  float m = s;
#pragma unroll
  for (int off = 8; off; off >>= 1) m = fmaxf(m, __shfl_xor(m, off, 64));
  float e = expf(s - m);
  float sum = e;
#pragma unroll
  for (int off = 8; off; off >>= 1) sum += __shfl_xor(sum, off, 64);
  att[t] = e / sum;
  __syncthreads();
  // output dim (h, j=i): sum over neighbors
  float o = 0.f;
#pragma unroll
  for (int k = 0; k < KNB; ++k) {
    const float* vrow = Vb + ((size_t)b * NN + nb[k]) * HH + h * DD;
    o += att[h * 16 + k] * vrow[i];
  }
  AO[(size_t)row * HH + t] = o;
}

// ---------------------------------------------------------------------------
// Kernel 5: fused pointer scores + tanh-clip + masked softmax -> probs
// workgroup: one b, GT g-rows, 256 threads; thread covers n=tid and tid+256
// tanh*10 <= 10, so exp(x-10) needs no max reduction.
// ---------------------------------------------------------------------------
__global__ __launch_bounds__(256) void pointer_kernel(
    const float* __restrict__ FQ, const float* __restrict__ emb,
    const float* __restrict__ mask, float* __restrict__ out) {
  int tile = blockIdx.x;
  int b = tile / NTILES;
  int g0 = (tile % NTILES) * GT;
  int gc = min(GT, GG - g0);
  int tid = threadIdx.x;
  __shared__ float fq[GT][HH];
  for (int i = tid; i < GT * HH; i += 256) {
    fq[i >> 7][i & 127] = (i < gc * HH)
        ? FQ[((size_t)(b * GG + g0)) * HH + i] : 0.f;
  }
  __syncthreads();

  int n1 = tid;
  int n2 = tid + 256;
  bool v2 = (n2 < NN);
  int n2c = v2 ? n2 : n1;
  const float4* e1 = (const float4*)(emb + ((size_t)b * NN + n1) * HH);
  const float4* e2 = (const float4*)(emb + ((size_t)b * NN + n2c) * HH);

  float acc1[GT], acc2[GT];
#pragma unroll
  for (int g = 0; g < GT; ++g) { acc1[g] = 0.f; acc2[g] = 0.f; }

#pragma unroll 4
  for (int k4 = 0; k4 < HH / 4; ++k4) {
    float4 a = e1[k4];
    float4 c = e2[k4];
#pragma unroll
    for (int g = 0; g < GT; ++g) {
      float4 w = *(const float4*)&fq[g][k4 * 4];  // LDS broadcast
      acc1[g] += a.x * w.x + a.y * w.y + a.z * w.z + a.w * w.w;
      acc2[g] += c.x * w.x + c.y * w.y + c.z * w.z + c.w * w.w;
    }
  }

  float p1[GT], p2[GT];
#pragma unroll
  for (int g = 0; g < GT; ++g) {
    float mk1 = 0.f, mk2 = 0.f;
    if (g < gc) {
      size_t mrow = (size_t)(b * GG + g0 + g) * NN;
      mk1 = mask[mrow + n1];
      mk2 = v2 ? mask[mrow + n2] : 0.f;
    }
    p1[g] = expf(tanhf(acc1[g]) * 10.f - 10.f + mk1);
    p2[g] = v2 ? expf(tanhf(acc2[g]) * 10.f - 10.f + mk2) : 0.f;
  }

  // per-g block sum: wave reduce then cross-wave via LDS
  __shared__ float wsums[4][GT];
  __shared__ float tot[GT];
  int lane = tid & 63;
  int w = tid >> 6;
#pragma unroll
  for (int g = 0; g < GT; ++g) {
    float s = p1[g] + p2[g];
#pragma unroll
    for (int off = 32; off; off >>= 1) s += __shfl_xor(s, off, 64);
    if (lane == 0) wsums[w][g] = s;
  }
  __syncthreads();
  if (tid < GT)
    tot[tid] = wsums[0][tid] + wsums[1][tid] + wsums[2][tid] + wsums[3][tid];
  __syncthreads();

#pragma unroll
  for (int g = 0; g < GT; ++g) {
    if (g < gc) {
      float inv = 1.f / tot[g];
      size_t orow = (size_t)(b * GG + g0 + g) * NN;
      out[orow + n1] = p1[g] * inv;
      if (v2) out[orow + n2] = p2[g] * inv;
    }
  }
}

// ---------------------------------------------------------------------------
extern "C" void kernel_launch(void* const* d_in, const int* in_sizes, int n_in,
                              void* d_out, int out_size, void* d_ws,
                              size_t ws_size, hipStream_t stream) {
  const float* coords    = (const float*)d_in[0];
  const float* emb       = (const float*)d_in[1];
  const int*   last_node = (const int*)d_in[2];
  const float* mask      = (const float*)d_in[3];
  const float* Wqg       = (const float*)d_in[4];
  const float* Wqf       = (const float*)d_in[5];
  const float* Wql       = (const float*)d_in[6];
  const float* Wk        = (const float*)d_in[7];
  const float* Wv        = (const float*)d_in[8];
  const float* Wc        = (const float*)d_in[9];
  const float* bc        = (const float*)d_in[10];
  // d_in[11] = n_neighbors (assumed 16, compiled in)

  float* wsf    = (float*)d_ws;
  float* Wsum   = wsf;                       // 128*128
  float* qgraph = Wsum + HH * HH;            // 32*128
  float* Kb     = qgraph + BB * HH;          // 32*500*128
  float* Vb     = Kb + (size_t)BB * NN * HH;
  float* Qb     = Vb + (size_t)BB * NN * HH; // also reused for final_q
  float* AO     = Qb + (size_t)BB * GG * HH;
  int*   nbr    = (int*)(AO + (size_t)BB * GG * HH);
  float* outp   = (float*)d_out;

  prep_kernel<<<BB + 1, 256, 0, stream>>>(emb, Wqg, Wqf, Wql, Wsum, qgraph);
  proj_kernel<<<500, 256, 0, stream>>>(emb, nullptr, Wk, nullptr, Kb, 0);
  proj_kernel<<<500, 256, 0, stream>>>(emb, nullptr, Wv, nullptr, Vb, 0);
  proj_kernel<<<500, 256, 0, stream>>>(emb, last_node, Wsum, qgraph, Qb, 1);
  topk_kernel<<<4000, 256, 0, stream>>>(coords, last_node, mask, nbr);
  attn_kernel<<<BB * GG, 128, 0, stream>>>(Qb, Kb, Vb, nbr, AO);
  proj_kernel<<<500, 256, 0, stream>>>(AO, nullptr, Wc, bc, Qb, 2);
  pointer_kernel<<<BB * NTILES, 256, 0, stream>>>(Qb, emb, mask, outp);
}

// Round 2
// 298.876 us; speedup vs baseline: 1.3167x; 1.3167x over previous
//
#include <hip/hip_runtime.h>
#include <math.h>

#define BB 32
#define NN 500
#define GG 500
#define HH 128
#define NHEADS 8
#define DD 16
#define KNB 16
#define GT 8           // g-rows per workgroup in pointer kernel
#define NTILES 63      // ceil(500/8)
#define MCHUNK 25      // mean-reduction chunks per batch
#define MROWS 20       // rows per chunk (25*20 = 500)

// ---------------------------------------------------------------------------
// Kernel 1a: partial sums for graph mean (32*25 blocks) + Wsum add (16 blocks)
// ---------------------------------------------------------------------------
__global__ __launch_bounds__(128) void mean_partial_kernel(
    const float* __restrict__ emb, const float* __restrict__ Wqf,
    const float* __restrict__ Wql, float* __restrict__ partial,
    float* __restrict__ Wsum) {
  int blk = blockIdx.x;
  int tid = threadIdx.x;
  if (blk >= BB * MCHUNK) {  // Wsum = Wqf + Wql, float4, 16 blocks
    int idx = (blk - BB * MCHUNK) * 128 + tid;
    const float4* f4 = (const float4*)Wqf;
    const float4* l4 = (const float4*)Wql;
    float4* s4 = (float4*)Wsum;
    for (int i = idx; i < (HH * HH) / 4; i += 2048) {
      float4 a = f4[i], c = l4[i];
      s4[i] = make_float4(a.x + c.x, a.y + c.y, a.z + c.z, a.w + c.w);
    }
    return;
  }
  int b = blk / MCHUNK;
  int chunk = blk % MCHUNK;
  const float* eb = emb + ((size_t)b * NN + chunk * MROWS) * HH;
  float acc = 0.f;
#pragma unroll
  for (int n = 0; n < MROWS; ++n) acc += eb[n * HH + tid];
  partial[(size_t)blk * HH + tid] = acc;
}

// ---------------------------------------------------------------------------
// Kernel 1b: reduce partials -> mean, project through Wqg -> qgraph (B,H)
// ---------------------------------------------------------------------------
__global__ __launch_bounds__(128) void qgraph_kernel(
    const float* __restrict__ partial, const float* __restrict__ Wqg,
    float* __restrict__ qgraph) {
  int b = blockIdx.x;
  int tid = threadIdx.x;
  __shared__ float meanv[HH];
  const float* p = partial + (size_t)b * MCHUNK * HH;
  float acc = 0.f;
#pragma unroll
  for (int c = 0; c < MCHUNK; ++c) acc += p[c * HH + tid];
  meanv[tid] = acc * (1.0f / NN);
  __syncthreads();
  const float4* wrow = (const float4*)(Wqg + (size_t)tid * HH);
  float s = 0.f;
#pragma unroll
  for (int k = 0; k < HH / 4; ++k) {
    float4 w = wrow[k];
    s += meanv[4 * k] * w.x + meanv[4 * k + 1] * w.y +
         meanv[4 * k + 2] * w.z + meanv[4 * k + 3] * w.w;
  }
  qgraph[b * HH + tid] = s;
}

// ---------------------------------------------------------------------------
// Kernel 2: generic projection out[row][o] = sum_k A[arow][k]*W[o][k] + bias
//   gather != nullptr : arow = b*NN + gather[row]   (last-node gather)
//   mode 0: no bias;  mode 1: + bias[b*HH + o] (q_graph);  mode 2: + bias[o]
// ---------------------------------------------------------------------------
__global__ __launch_bounds__(256) void proj_kernel(
    const float* __restrict__ A, const int* __restrict__ gather,
    const float* __restrict__ W, const float* __restrict__ bias,
    float* __restrict__ out, int mode) {
  __shared__ float As[32][36];    // [k][row]
  __shared__ float Ws[32][132];   // [k][col]
  int tid = threadIdx.x;
  int row0 = blockIdx.x * 32;

  float acc[4][4];
#pragma unroll
  for (int i = 0; i < 4; ++i)
#pragma unroll
    for (int j = 0; j < 4; ++j) acc[i][j] = 0.f;

  int cg = tid & 31; int c0 = cg * 4;
  int rg = tid >> 5; int r0 = rg * 4;

  int sr = tid >> 3;
  int skq = tid & 7;
  int grow = row0 + sr;
  int arow;
  if (gather) {
    int bofr = grow / GG;
    arow = bofr * NN + gather[grow];
  } else {
    arow = grow;
  }
  const float4* Arow4 = (const float4*)(A + (size_t)arow * HH);

  for (int ks = 0; ks < 4; ++ks) {
    int k0 = ks * 32;
    float4 a4 = Arow4[(k0 >> 2) + skq];
    As[skq * 4 + 0][sr] = a4.x;
    As[skq * 4 + 1][sr] = a4.y;
    As[skq * 4 + 2][sr] = a4.z;
    As[skq * 4 + 3][sr] = a4.w;
#pragma unroll
    for (int j = 0; j < 4; ++j) {
      int f = tid + j * 256;
      int o = f >> 3; int kq = f & 7;
      float4 w4 = *(const float4*)(W + (size_t)o * HH + k0 + kq * 4);
      Ws[kq * 4 + 0][o] = w4.x;
      Ws[kq * 4 + 1][o] = w4.y;
      Ws[kq * 4 + 2][o] = w4.z;
      Ws[kq * 4 + 3][o] = w4.w;
    }
    __syncthreads();
#pragma unroll
    for (int k = 0; k < 32; ++k) {
      float4 av = *(const float4*)&As[k][r0];
      float4 wv = *(const float4*)&Ws[k][c0];
      acc[0][0] += av.x * wv.x; acc[0][1] += av.x * wv.y;
      acc[0][2] += av.x * wv.z; acc[0][3] += av.x * wv.w;
      acc[1][0] += av.y * wv.x; acc[1][1] += av.y * wv.y;
      acc[1][2] += av.y * wv.z; acc[1][3] += av.y * wv.w;
      acc[2][0] += av.z * wv.x; acc[2][1] += av.z * wv.y;
      acc[2][2] += av.z * wv.z; acc[2][3] += av.z * wv.w;
      acc[3][0] += av.w * wv.x; acc[3][1] += av.w * wv.y;
      acc[3][2] += av.w * wv.z; acc[3][3] += av.w * wv.w;
    }
    __syncthreads();
  }

#pragma unroll
  for (int i = 0; i < 4; ++i) {
    int orow = row0 + r0 + i;
    float b0 = 0.f, b1 = 0.f, b2 = 0.f, b3 = 0.f;
    if (mode == 1) {
      int bofr = orow / GG;
      const float* qg = bias + bofr * HH + c0;
      b0 = qg[0]; b1 = qg[1]; b2 = qg[2]; b3 = qg[3];
    } else if (mode == 2) {
      b0 = bias[c0 + 0]; b1 = bias[c0 + 1]; b2 = bias[c0 + 2]; b3 = bias[c0 + 3];
    }
    float4 o4;
    o4.x = acc[i][0] + b0; o4.y = acc[i][1] + b1;
    o4.z = acc[i][2] + b2; o4.w = acc[i][3] + b3;
    *(float4*)(out + (size_t)orow * HH + c0) = o4;
  }
}

// ---------------------------------------------------------------------------
// Kernel 3: per-(b,g) distances + stable top-16 smallest (one wave per row)
// ---------------------------------------------------------------------------
__global__ __launch_bounds__(256) void topk_kernel(
    const float* __restrict__ coords, const int* __restrict__ last_node,
    const float* __restrict__ mask, int* __restrict__ nbr) {
  int lane = threadIdx.x & 63;
  int wid = threadIdx.x >> 6;
  int row = blockIdx.x * 4 + wid;
  if (row >= BB * GG) return;
  int b = row / GG;
  int last = last_node[row];
  const float* cb = coords + (size_t)b * NN * 2;
  float lx = cb[(size_t)last * 2 + 0];
  float ly = cb[(size_t)last * 2 + 1];
  const float* mrow = mask + (size_t)row * NN;

  float dv[8];
#pragma unroll
  for (int j = 0; j < 8; ++j) {
    int n = lane + j * 64;
    float d = INFINITY;
    if (n < NN) {
      float dx = lx - cb[n * 2];
      float dy = ly - cb[n * 2 + 1];
      d = sqrtf(dx * dx + dy * dy);
      if (mrow[n] == -INFINITY) d = INFINITY;
    }
    dv[j] = d;
  }

  int mine = 0;
  for (int r = 0; r < KNB; ++r) {
    float bv = dv[0]; int bj = 0;
#pragma unroll
    for (int j = 1; j < 8; ++j) {
      if (dv[j] < bv) { bv = dv[j]; bj = j; }
    }
    int bn = lane + bj * 64;
#pragma unroll
    for (int off = 32; off; off >>= 1) {
      float ov = __shfl_xor(bv, off, 64);
      int on = __shfl_xor(bn, off, 64);
      if (ov < bv || (ov == bv && on < bn)) { bv = ov; bn = on; }
    }
    if ((bn & 63) == lane) {
      int jw = bn >> 6;
#pragma unroll
      for (int j = 0; j < 8; ++j)
        if (j == jw) dv[j] = INFINITY;
    }
    if (lane == r) mine = bn;
  }
  if (lane < KNB) nbr[(size_t)row * KNB + lane] = mine;
}

// ---------------------------------------------------------------------------
// Kernel 4: sparse glimpse attention over 16 neighbors + head concat
// ---------------------------------------------------------------------------
__global__ __launch_bounds__(128) void attn_kernel(
    const float* __restrict__ Q, const float* __restrict__ Kb,
    const float* __restrict__ Vb, const int* __restrict__ nbr,
    float* __restrict__ AO) {
  int row = blockIdx.x;
  int b = row / GG;
  int t = threadIdx.x;
  __shared__ float qs[HH];
  __shared__ int nb[KNB];
  __shared__ float att[HH];
  qs[t] = Q[(size_t)row * HH + t];
  if (t < KNB) nb[t] = nbr[(size_t)row * KNB + t];
  __syncthreads();
  int h = t >> 4;
  int i = t & 15;
  const float* krow = Kb + ((size_t)b * NN + nb[i]) * HH + h * DD;
  float s = 0.f;
#pragma unroll
  for (int j = 0; j < DD; ++j) s += qs[h * DD + j] * krow[j];
  s *= 0.25f;
  float m = s;
#pragma unroll
  for (int off = 8; off; off >>= 1) m = fmaxf(m, __shfl_xor(m, off, 64));
  float e = __expf(s - m);
  float sum = e;
#pragma unroll
  for (int off = 8; off; off >>= 1) sum += __shfl_xor(sum, off, 64);
  att[t] = e / sum;
  __syncthreads();
  float o = 0.f;
#pragma unroll
  for (int k = 0; k < KNB; ++k) {
    const float* vrow = Vb + ((size_t)b * NN + nb[k]) * HH + h * DD;
    o += att[h * 16 + k] * vrow[i];
  }
  AO[(size_t)row * HH + t] = o;
}

// ---------------------------------------------------------------------------
// Kernel 5: fused pointer scores + tanh-clip + masked softmax -> probs
// tanh(x)*10 = 10 - 20/(exp(2x)+1); exp(t-10+mask), no max reduction needed.
// ---------------------------------------------------------------------------
__global__ __launch_bounds__(256) void pointer_kernel(
    const float* __restrict__ FQ, const float* __restrict__ emb,
    const float* __restrict__ mask, float* __restrict__ out) {
  int tile = blockIdx.x;
  int b = tile / NTILES;
  int g0 = (tile % NTILES) * GT;
  int gc = min(GT, GG - g0);
  int tid = threadIdx.x;
  __shared__ float fq[GT][HH];
  for (int i = tid; i < GT * HH; i += 256) {
    fq[i >> 7][i & 127] = (i < gc * HH)
        ? FQ[((size_t)(b * GG + g0)) * HH + i] : 0.f;
  }
  __syncthreads();

  int n1 = tid;
  int n2 = tid + 256;
  bool v2 = (n2 < NN);
  int n2c = v2 ? n2 : n1;
  const float4* e1 = (const float4*)(emb + ((size_t)b * NN + n1) * HH);
  const float4* e2 = (const float4*)(emb + ((size_t)b * NN + n2c) * HH);

  float acc1[GT], acc2[GT];
#pragma unroll
  for (int g = 0; g < GT; ++g) { acc1[g] = 0.f; acc2[g] = 0.f; }

#pragma unroll 4
  for (int k4 = 0; k4 < HH / 4; ++k4) {
    float4 a = e1[k4];
    float4 c = e2[k4];
#pragma unroll
    for (int g = 0; g < GT; ++g) {
      float4 w = *(const float4*)&fq[g][k4 * 4];
      acc1[g] += a.x * w.x + a.y * w.y + a.z * w.z + a.w * w.w;
      acc2[g] += c.x * w.x + c.y * w.y + c.z * w.z + c.w * w.w;
    }
  }

  float p1[GT], p2[GT];
#pragma unroll
  for (int g = 0; g < GT; ++g) {
    float mk1 = 0.f, mk2 = 0.f;
    if (g < gc) {
      size_t mrow = (size_t)(b * GG + g0 + g) * NN;
      mk1 = mask[mrow + n1];
      mk2 = v2 ? mask[mrow + n2] : 0.f;
    }
    // tanh(x)*10 via fast exp: 10 - 20/(e^{2x}+1); +/-inf safe
    float t1 = 10.f - 20.f / (__expf(2.f * acc1[g]) + 1.f);
    float t2 = 10.f - 20.f / (__expf(2.f * acc2[g]) + 1.f);
    p1[g] = __expf(t1 - 10.f + mk1);
    p2[g] = v2 ? __expf(t2 - 10.f + mk2) : 0.f;
  }

  __shared__ float wsums[4][GT];
  __shared__ float tot[GT];
  int lane = tid & 63;
  int w = tid >> 6;
#pragma unroll
  for (int g = 0; g < GT; ++g) {
    float s = p1[g] + p2[g];
#pragma unroll
    for (int off = 32; off; off >>= 1) s += __shfl_xor(s, off, 64);
    if (lane == 0) wsums[w][g] = s;
  }
  __syncthreads();
  if (tid < GT)
    tot[tid] = wsums[0][tid] + wsums[1][tid] + wsums[2][tid] + wsums[3][tid];
  __syncthreads();

#pragma unroll
  for (int g = 0; g < GT; ++g) {
    if (g < gc) {
      float inv = 1.f / tot[g];
      size_t orow = (size_t)(b * GG + g0 + g) * NN;
      out[orow + n1] = p1[g] * inv;
      if (v2) out[orow + n2] = p2[g] * inv;
    }
  }
}

// ---------------------------------------------------------------------------
extern "C" void kernel_launch(void* const* d_in, const int* in_sizes, int n_in,
                              void* d_out, int out_size, void* d_ws,
                              size_t ws_size, hipStream_t stream) {
  const float* coords    = (const float*)d_in[0];
  const float* emb       = (const float*)d_in[1];
  const int*   last_node = (const int*)d_in[2];
  const float* mask      = (const float*)d_in[3];
  const float* Wqg       = (const float*)d_in[4];
  const float* Wqf       = (const float*)d_in[5];
  const float* Wql       = (const float*)d_in[6];
  const float* Wk        = (const float*)d_in[7];
  const float* Wv        = (const float*)d_in[8];
  const float* Wc        = (const float*)d_in[9];
  const float* bc        = (const float*)d_in[10];

  float* wsf    = (float*)d_ws;
  float* Wsum   = wsf;                       // 128*128
  float* qgraph = Wsum + HH * HH;            // 32*128
  float* Kb     = qgraph + BB * HH;          // 32*500*128
  float* Vb     = Kb + (size_t)BB * NN * HH;
  float* Qb     = Vb + (size_t)BB * NN * HH; // also reused for final_q
  float* AO     = Qb + (size_t)BB * GG * HH;
  int*   nbr    = (int*)(AO + (size_t)BB * GG * HH);
  float* partial = (float*)(nbr + (size_t)BB * GG * KNB);  // 32*25*128

  float* outp   = (float*)d_out;

  mean_partial_kernel<<<BB * MCHUNK + 16, 128, 0, stream>>>(emb, Wqf, Wql,
                                                            partial, Wsum);
  qgraph_kernel<<<BB, 128, 0, stream>>>(partial, Wqg, qgraph);
  proj_kernel<<<500, 256, 0, stream>>>(emb, nullptr, Wk, nullptr, Kb, 0);
  proj_kernel<<<500, 256, 0, stream>>>(emb, nullptr, Wv, nullptr, Vb, 0);
  proj_kernel<<<500, 256, 0, stream>>>(emb, last_node, Wsum, qgraph, Qb, 1);
  topk_kernel<<<4000, 256, 0, stream>>>(coords, last_node, mask, nbr);
  attn_kernel<<<BB * GG, 128, 0, stream>>>(Qb, Kb, Vb, nbr, AO);
  proj_kernel<<<500, 256, 0, stream>>>(AO, nullptr, Wc, bc, Qb, 2);
  pointer_kernel<<<BB * NTILES, 256, 0, stream>>>(Qb, emb, mask, outp);
}